// Round 7
// baseline (101.308 us; speedup 1.0000x reference)
//
#include <hip/hip_runtime.h>
#include <math.h>

#define NT 512
#define QDIM 4096   // 2^12
#define GT_STRIDE 640   // floats per batch in gate table: 72 mats * 8 + 36 zhalf (+pad)

using F2 = float2;

__device__ __forceinline__ F2 cadd(F2 p, F2 q) { return make_float2(p.x + q.x, p.y + q.y); }
__device__ __forceinline__ F2 cmul(F2 p, F2 q) {
    return make_float2(p.x * q.x - p.y * q.y, p.x * q.y + p.y * q.x);
}

struct M2 { F2 a, b, c, d; };  // [[a,b],[c,d]]

__device__ __forceinline__ M2 mmul(M2 A, M2 B) {
    M2 R;
    R.a = cadd(cmul(A.a, B.a), cmul(A.b, B.c));
    R.b = cadd(cmul(A.a, B.b), cmul(A.b, B.d));
    R.c = cadd(cmul(A.c, B.a), cmul(A.d, B.c));
    R.d = cadd(cmul(A.c, B.b), cmul(A.d, B.d));
    return R;
}

__device__ __forceinline__ M2 mrx(float t) {
    float s, c; sincosf(0.5f * t, &s, &c);
    return { make_float2(c, 0), make_float2(0, -s), make_float2(0, -s), make_float2(c, 0) };
}
__device__ __forceinline__ M2 mry(float t) {
    float s, c; sincosf(0.5f * t, &s, &c);
    return { make_float2(c, 0), make_float2(-s, 0), make_float2(s, 0), make_float2(c, 0) };
}
__device__ __forceinline__ M2 mrz(float t) {
    float s, c; sincosf(0.5f * t, &s, &c);
    return { make_float2(c, -s), make_float2(0, 0), make_float2(0, 0), make_float2(c, s) };
}

#define RSQ2 0.70710678118654752f
__device__ __forceinline__ M2 mH() {   // H
    return { make_float2(RSQ2, 0), make_float2(RSQ2, 0), make_float2(RSQ2, 0), make_float2(-RSQ2, 0) };
}
__device__ __forceinline__ M2 mW() {   // W = H*S; W† Z W = -Y => YY = W†⊗W† ZZ W⊗W
    return { make_float2(RSQ2, 0), make_float2(0, RSQ2), make_float2(RSQ2, 0), make_float2(0, -RSQ2) };
}
__device__ __forceinline__ M2 mWd() {  // W†
    return { make_float2(RSQ2, 0), make_float2(RSQ2, 0), make_float2(0, -RSQ2), make_float2(0, RSQ2) };
}

// ============ prep kernel: fused gate tables -> d_ws (wave-uniform data) ============
__global__ __launch_bounds__(128) void prep_kernel(
    const float* __restrict__ data, const float* __restrict__ enc_scale,
    const float* __restrict__ enc_bias, const float* __restrict__ eta,
    const float* __restrict__ ew_zz, const float* __restrict__ ew_xx,
    const float* __restrict__ ew_yy, const float* __restrict__ nb_z,
    const float* __restrict__ nb_x, const float* __restrict__ nb_y,
    const float* __restrict__ trots, float* __restrict__ gt)
{
    const int bat = blockIdx.x, tid = threadIdx.x;
    float* g = gt + bat * GT_STRIDE;
    if (tid < 36) {                      // encoding (+opening basis change): b = tid/12, q = tid%12
        int b = tid / 12, q = tid % 12;
        float x  = data[bat * 12 + q];
        float ax = enc_scale[q * 3 + 0] * x + enc_bias[q * 3 + 0];
        float ay = enc_scale[q * 3 + 1] * x + enc_bias[q * 3 + 1];
        float az = enc_scale[q * 3 + 2] * x + enc_bias[q * 3 + 2];
        M2 M;
        if (b == 0)      M = mmul(mrz(az), mmul(mry(ay), mrx(ax)));   // ZZ: no basis change
        else if (b == 1) M = mmul(mH(), mmul(mry(ay), mrx(ax)));      // XX: H after enc
        else             M = mmul(mW(), mmul(mrz(az), mry(ay)));      // YY: W after enc
        float* o = g + tid * 8;
        o[0] = M.a.x; o[1] = M.a.y; o[2] = M.b.x; o[3] = M.b.y;
        o[4] = M.c.x; o[5] = M.c.y; o[6] = M.d.x; o[7] = M.d.y;
    } else if (tid < 72) {               // bias + trainables (+ closing basis change first)
        int i = tid - 36, b = i / 12, q = i % 12;
        float nb = (b == 0) ? nb_z[q] : (b == 1) ? nb_x[q] : nb_y[q];
        M2 M0 = (b == 0) ? mrz(nb) : (b == 1) ? mrx(nb) : mry(nb);
        float t0 = trots[(b * 12 + q) * 3 + 0];
        float t1 = trots[(b * 12 + q) * 3 + 1];
        float t2 = trots[(b * 12 + q) * 3 + 2];
        M2 M = mmul(mrz(t2), mmul(mry(t1), mmul(mrx(t0), M0)));
        if (b == 1)      M = mmul(M, mH());    // closes the XX sandwich
        else if (b == 2) M = mmul(M, mWd());   // closes the YY sandwich
        float* o = g + tid * 8;
        o[0] = M.a.x; o[1] = M.a.y; o[2] = M.b.x; o[3] = M.b.y;
        o[4] = M.c.x; o[5] = M.c.y; o[6] = M.d.x; o[7] = M.d.y;
    } else if (tid < 108) {              // diagonal half-angles per block/edge
        int i = tid - 72, b = i / 12, e = i % 12;
        const float* ew = (b == 0) ? ew_zz : (b == 1) ? ew_xx : ew_yy;
        g[576 + i] = 0.5f * eta[b] * ew[e];
    }
}

// ================= layouts =================
// tid = wv*64 + l.  Layout Li: register-local j = qubits {3Li..3Li+2}
// L0: k = j | l<<3 | wv<<9          L1: k = (l&7) | j<<3 | (l>>3)<<6 | wv<<9
// L2: k = l | j<<6 | wv<<9          L3: k = l | wv<<6 | j<<9

template<int Li>
__device__ __forceinline__ int kOf(int t, int j) {
    const int mlo = (1 << (3 * Li)) - 1;
    return (t & mlo) | (j << (3 * Li)) | ((t & ~mlo) << 3);
}
__device__ __forceinline__ int slot0(int k) {   // L0 barrier-buffer slot (matches btrip writes)
    int j = k & 7, t = k >> 3;
    return j * 512 + (t ^ j);
}

// ---- intra-wave trips (wave-private 512-F2 region wb, NO barrier) ----
template<int TYPE>   // TYPE 0: <0,1>/<1,0>   TYPE 1: <1,2>/<2,1>
__device__ __forceinline__ void itrip(F2* amp, int l, F2* wb) {
#pragma unroll
    for (int j = 0; j < 8; ++j) wb[j * 64 + (l ^ ((9 * j) & 63))] = amp[j];
    asm volatile("" ::: "memory");   // compiler fence; DS pipe is in-order per wave
#pragma unroll
    for (int j = 0; j < 8; ++j) {
        int jo, lo;
        if (TYPE == 0) { jo = l & 7;        lo = j | (l & 56); }
        else           { jo = (l >> 3) & 7; lo = (l & 7) | (j << 3); }
        amp[j] = wb[jo * 64 + (lo ^ ((9 * jo) & 63))];
    }
}

// ---- barrier trip <2,3> / <3,2> (involution: same formula both ways) ----
__device__ __forceinline__ void btrip(F2* amp, int tid, int l, int wv, F2* b) {
#pragma unroll
    for (int j = 0; j < 8; ++j) b[j * 512 + (tid ^ j)] = amp[j];
    __syncthreads();
#pragma unroll
    for (int j = 0; j < 8; ++j) amp[j] = b[wv * 512 + ((j * 64 + l) ^ wv)];
}

// ---- 1q register gate on local j-bit JB; g points at 8 floats in global (uniform) ----
template<int JB>
__device__ __forceinline__ void g1_reg(F2* amp, const float* __restrict__ g) {
    const int m = 1 << JB;
    F2 m00 = make_float2(g[0], g[1]), m01 = make_float2(g[2], g[3]);
    F2 m10 = make_float2(g[4], g[5]), m11 = make_float2(g[6], g[7]);
#pragma unroll
    for (int j = 0; j < 8; ++j)
        if (!(j & m)) {
            F2 a = amp[j], b = amp[j | m];
            amp[j]     = cadd(cmul(m00, a), cmul(m01, b));
            amp[j | m] = cadd(cmul(m10, a), cmul(m11, b));
        }
}

// ---- fused diagonal Ising phase (all 12 ring edges) in L3: k = tid(0-8) | j<<9 ----
__device__ __forceinline__ void diag_L3(F2* amp, const float* __restrict__ zh, int tid) {
    float phi0 = 0.f;
#pragma unroll
    for (int e = 3; e <= 10; ++e) {   // edges entirely in tid bits: thread-constant
        int hi = 11 - e, lo = 10 - e;
        phi0 += (((tid >> hi) ^ (tid >> lo)) & 1) ? zh[e] : -zh[e];
    }
    float z0 = zh[0], z1 = zh[1], z2 = zh[2], z11 = zh[11];
    int t8 = (tid >> 8) & 1, t0 = tid & 1;
#pragma unroll
    for (int j = 0; j < 8; ++j) {
        int j0 = j & 1, j1 = (j >> 1) & 1, j2 = (j >> 2) & 1;
        float phi = phi0
            + ((j2 ^ j1) ? z0 : -z0)       // (11,10)
            + ((j1 ^ j0) ? z1 : -z1)       // (10,9)
            + ((j0 ^ t8) ? z2 : -z2)       // (9,8)
            + ((j2 ^ t0) ? z11 : -z11);    // (11,0)
        float sp, cp;
        __sincosf(phi, &sp, &cp);
        amp[j] = cmul(amp[j], make_float2(cp, sp));
    }
}

// ---- composed CNOT-ring source index ----
__device__ __forceinline__ int cnot_src(int k) {
#pragma unroll
    for (int e = 11; e >= 0; --e) {
        int hi = (e < 11) ? 11 - e : 11, lo = (e < 11) ? 10 - e : 0;
        if ((k >> hi) & 1) k ^= (1 << lo);
    }
    return k;
}

__device__ __forceinline__ void cnot_trip(F2* amp, int tid, const int* kslot, F2* b) {
#pragma unroll
    for (int j = 0; j < 8; ++j) b[j * 512 + (tid ^ j)] = amp[j];  // L0 write
    __syncthreads();
#pragma unroll
    for (int j = 0; j < 8; ++j) amp[j] = b[kslot[j]];             // lands in L0
}

__global__ __launch_bounds__(NT) void qsim_kernel(
    const float* __restrict__ gt,   // per-batch fused gate tables (from prep_kernel)
    float* __restrict__ out)        // [64,12]
{
    __shared__ F2 bbuf[2][QDIM];   // 64 KB barrier double buffer
    __shared__ F2 ibuf[QDIM];      // 32 KB intra-wave buffer (512 F2 per wave)
    __shared__ float red[8][12];

    const int tid = threadIdx.x;
    const int l = tid & 63, wv = tid >> 6;
    const int bat = blockIdx.x;
    F2* wb = &ibuf[wv * 512];      // wave-private region
    const float* __restrict__ G = gt + bat * GT_STRIDE;   // uniform base -> scalar loads

    // ---- state: L0, k = (tid<<3)|j ----
    F2 amp[8];
#pragma unroll
    for (int j = 0; j < 8; ++j) amp[j] = make_float2(0.f, 0.f);
    if (tid == 0) amp[0].x = 1.f;

    // precompute CNOT-ring gather slots (same permutation every block)
    int kslot[8];
#pragma unroll
    for (int j = 0; j < 8; ++j)
        kslot[j] = slot0(cnot_src(kOf<0>(tid, j)));

    int sel = 0;
#define NB (&bbuf[(sel ^= 1) ^ 1][0])

    for (int blk = 0; blk < 3; ++blk) {
        const float* Ge = G + blk * 96;          // 12 mats * 8 floats
        const float* Gb = G + 288 + blk * 96;
        const float* zh = G + 576 + blk * 12;

        // ---- encoding (+opening basis change): L0 -> L1 -> L2 -> L3 ----
        g1_reg<0>(amp, Ge + 0);   g1_reg<1>(amp, Ge + 8);   g1_reg<2>(amp, Ge + 16);
        itrip<0>(amp, l, wb);                       // L0 -> L1 (no barrier)
        g1_reg<0>(amp, Ge + 24);  g1_reg<1>(amp, Ge + 32);  g1_reg<2>(amp, Ge + 40);
        itrip<1>(amp, l, wb);                       // L1 -> L2 (no barrier)
        g1_reg<0>(amp, Ge + 48);  g1_reg<1>(amp, Ge + 56);  g1_reg<2>(amp, Ge + 64);
        btrip(amp, tid, l, wv, NB);                 // L2 -> L3 (barrier)
        g1_reg<0>(amp, Ge + 72);  g1_reg<1>(amp, Ge + 80);  g1_reg<2>(amp, Ge + 88);

        // ---- Ising block == fused diagonal in the rotated basis (L3) ----
        diag_L3(amp, zh, tid);

        // ---- (closing basis change+) bias + trots: L3 -> L2 -> L1 -> L0 ----
        g1_reg<0>(amp, Gb + 72);  g1_reg<1>(amp, Gb + 80);  g1_reg<2>(amp, Gb + 88);
        btrip(amp, tid, l, wv, NB);                 // L3 -> L2 (barrier)
        g1_reg<0>(amp, Gb + 48);  g1_reg<1>(amp, Gb + 56);  g1_reg<2>(amp, Gb + 64);
        itrip<1>(amp, l, wb);                       // L2 -> L1 (no barrier)
        g1_reg<0>(amp, Gb + 24);  g1_reg<1>(amp, Gb + 32);  g1_reg<2>(amp, Gb + 40);
        itrip<0>(amp, l, wb);                       // L1 -> L0 (no barrier)
        g1_reg<0>(amp, Gb + 0);   g1_reg<1>(amp, Gb + 8);   g1_reg<2>(amp, Gb + 16);

        // ---- CNOT entangling ring (fused permutation, stays L0; barrier) ----
        cnot_trip(amp, tid, kslot, NB);
    }

    // ---- Pauli-Z expectations (state in L0: k = (tid<<3)|j) ----
    float pr[8];
#pragma unroll
    for (int j = 0; j < 8; ++j) pr[j] = amp[j].x * amp[j].x + amp[j].y * amp[j].y;
    float psum = 0.f;
#pragma unroll
    for (int j = 0; j < 8; ++j) psum += pr[j];

    float acc[12];
#pragma unroll
    for (int i = 0; i < 9; ++i)
        acc[i] = ((tid >> (8 - i)) & 1) ? -psum : psum;
#pragma unroll
    for (int i = 9; i < 12; ++i) {
        float s = 0.f;
        int bit = 11 - i;  // j-bit index
#pragma unroll
        for (int j = 0; j < 8; ++j)
            s += ((j >> bit) & 1) ? -pr[j] : pr[j];
        acc[i] = s;
    }
#pragma unroll
    for (int off = 32; off > 0; off >>= 1)
#pragma unroll
        for (int i = 0; i < 12; ++i)
            acc[i] += __shfl_down(acc[i], off, 64);
    if ((tid & 63) == 0)
#pragma unroll
        for (int i = 0; i < 12; ++i) red[wv][i] = acc[i];
    __syncthreads();
    if (tid < 12) {
        float s = 0.f;
#pragma unroll
        for (int ww = 0; ww < 8; ++ww) s += red[ww][tid];
        out[bat * 12 + tid] = s;
    }
}

extern "C" void kernel_launch(void* const* d_in, const int* in_sizes, int n_in,
                              void* d_out, int out_size, void* d_ws, size_t ws_size,
                              hipStream_t stream) {
    const float* data      = (const float*)d_in[0];
    const float* enc_scale = (const float*)d_in[1];
    const float* enc_bias  = (const float*)d_in[2];
    const float* eta       = (const float*)d_in[3];
    const float* ew_zz     = (const float*)d_in[4];
    const float* ew_xx     = (const float*)d_in[5];
    const float* ew_yy     = (const float*)d_in[6];
    const float* nb_z      = (const float*)d_in[7];
    const float* nb_x      = (const float*)d_in[8];
    const float* nb_y      = (const float*)d_in[9];
    const float* trots     = (const float*)d_in[10];
    float* out = (float*)d_out;
    float* gt  = (float*)d_ws;

    int batch = out_size / 12;  // 64
    prep_kernel<<<batch, 128, 0, stream>>>(data, enc_scale, enc_bias, eta,
                                           ew_zz, ew_xx, ew_yy,
                                           nb_z, nb_x, nb_y, trots, gt);
    qsim_kernel<<<batch, NT, 0, stream>>>(gt, out);
}

// Round 8
// 95.026 us; speedup vs baseline: 1.0661x; 1.0661x over previous
//
#include <hip/hip_runtime.h>
#include <math.h>

#define NT 512
#define QDIM 4096   // 2^12

typedef float v2f __attribute__((ext_vector_type(2)));
using F2 = float2;

__device__ __forceinline__ v2f mkv(float x, float y) { v2f r; r.x = x; r.y = y; return r; }

// ---- packed complex ops (VOP3P dual-FP32) ----
// cfma: r = acc + m*a  (complex), 2 instructions
__device__ __forceinline__ v2f cfma(v2f m, v2f a, v2f acc) {
    v2f r;
    asm("v_pk_fma_f32 %0, %1, %2, %3 op_sel:[0,0,0] op_sel_hi:[0,1,1]\n\t"
        "v_pk_fma_f32 %0, %1, %2, %0 op_sel:[1,1,0] op_sel_hi:[1,0,1] neg_lo:[1,0,0]"
        : "=&v"(r) : "v"(m), "v"(a), "v"(acc));
    return r;
}
// cmulp: r = m*a (complex), 2 instructions
__device__ __forceinline__ v2f cmulp(v2f m, v2f a) {
    v2f r;
    asm("v_pk_mul_f32 %0, %1, %2 op_sel:[0,0] op_sel_hi:[0,1]\n\t"
        "v_pk_fma_f32 %0, %1, %2, %0 op_sel:[1,1,0] op_sel_hi:[1,0,1] neg_lo:[1,0,0]"
        : "=&v"(r) : "v"(m), "v"(a));
    return r;
}

// ---- host-style complex helpers for the table build (scalar, once per block) ----
__device__ __forceinline__ F2 cadd(F2 p, F2 q) { return make_float2(p.x + q.x, p.y + q.y); }
__device__ __forceinline__ F2 cmul(F2 p, F2 q) {
    return make_float2(p.x * q.x - p.y * q.y, p.x * q.y + p.y * q.x);
}
struct M2 { F2 a, b, c, d; };
__device__ __forceinline__ M2 mmul(M2 A, M2 B) {
    M2 R;
    R.a = cadd(cmul(A.a, B.a), cmul(A.b, B.c));
    R.b = cadd(cmul(A.a, B.b), cmul(A.b, B.d));
    R.c = cadd(cmul(A.c, B.a), cmul(A.d, B.c));
    R.d = cadd(cmul(A.c, B.b), cmul(A.d, B.d));
    return R;
}
__device__ __forceinline__ M2 mrx(float t) {
    float s, c; sincosf(0.5f * t, &s, &c);
    return { make_float2(c, 0), make_float2(0, -s), make_float2(0, -s), make_float2(c, 0) };
}
__device__ __forceinline__ M2 mry(float t) {
    float s, c; sincosf(0.5f * t, &s, &c);
    return { make_float2(c, 0), make_float2(-s, 0), make_float2(s, 0), make_float2(c, 0) };
}
__device__ __forceinline__ M2 mrz(float t) {
    float s, c; sincosf(0.5f * t, &s, &c);
    return { make_float2(c, -s), make_float2(0, 0), make_float2(0, 0), make_float2(c, s) };
}
#define RSQ2 0.70710678118654752f
__device__ __forceinline__ M2 mH() {
    return { make_float2(RSQ2, 0), make_float2(RSQ2, 0), make_float2(RSQ2, 0), make_float2(-RSQ2, 0) };
}
__device__ __forceinline__ M2 mW() {   // W = H*S; W† Z W = -Y => YY = W†⊗W† ZZ W⊗W
    return { make_float2(RSQ2, 0), make_float2(0, RSQ2), make_float2(RSQ2, 0), make_float2(0, -RSQ2) };
}
__device__ __forceinline__ M2 mWd() {
    return { make_float2(RSQ2, 0), make_float2(RSQ2, 0), make_float2(0, -RSQ2), make_float2(0, RSQ2) };
}

// ================= layouts =================
// tid = wv*64 + l.  Layout Li: register-local j = qubits {3Li..3Li+2}
// L0: k = j | l<<3 | wv<<9          L1: k = (l&7) | j<<3 | (l>>3)<<6 | wv<<9
// L2: k = l | j<<6 | wv<<9          L3: k = l | wv<<6 | j<<9

template<int Li>
__device__ __forceinline__ int kOf(int t, int j) {
    const int mlo = (1 << (3 * Li)) - 1;
    return (t & mlo) | (j << (3 * Li)) | ((t & ~mlo) << 3);
}
__device__ __forceinline__ int slot0(int k) {
    int j = k & 7, t = k >> 3;
    return j * 512 + (t ^ j);
}

// ---- intra-wave trips (wave-private 512-v2f region wb, NO barrier) ----
template<int TYPE>   // TYPE 0: <0,1>/<1,0>   TYPE 1: <1,2>/<2,1>
__device__ __forceinline__ void itrip(v2f* amp, int l, v2f* wb) {
#pragma unroll
    for (int j = 0; j < 8; ++j) wb[j * 64 + (l ^ ((9 * j) & 63))] = amp[j];
    asm volatile("" ::: "memory");   // compiler fence; DS pipe is in-order per wave
#pragma unroll
    for (int j = 0; j < 8; ++j) {
        int jo, lo;
        if (TYPE == 0) { jo = l & 7;        lo = j | (l & 56); }
        else           { jo = (l >> 3) & 7; lo = (l & 7) | (j << 3); }
        amp[j] = wb[jo * 64 + (lo ^ ((9 * jo) & 63))];
    }
}

// ---- barrier trip <2,3> / <3,2> (involution: same formula both ways) ----
__device__ __forceinline__ void btrip(v2f* amp, int tid, int l, int wv, v2f* b) {
#pragma unroll
    for (int j = 0; j < 8; ++j) b[j * 512 + (tid ^ j)] = amp[j];
    __syncthreads();
#pragma unroll
    for (int j = 0; j < 8; ++j) amp[j] = b[wv * 512 + ((j * 64 + l) ^ wv)];
}

// ---- 1q register gate on local j-bit JB (packed math; g = 4 v2f in LDS, uniform) ----
template<int JB>
__device__ __forceinline__ void g1_reg(v2f* amp, const v2f* g) {
    const int m = 1 << JB;
    v2f m00 = g[0], m01 = g[1], m10 = g[2], m11 = g[3];
#pragma unroll
    for (int j = 0; j < 8; ++j)
        if (!(j & m)) {
            v2f a = amp[j], b = amp[j | m];
            amp[j]     = cfma(m01, b, cmulp(m00, a));
            amp[j | m] = cfma(m11, b, cmulp(m10, a));
        }
}

// ---- fused diagonal Ising phase (all 12 ring edges) in L3: k = tid(0-8) | j<<9 ----
__device__ __forceinline__ void diag_L3(v2f* amp, const float* zh, int tid) {
    float phi0 = 0.f;
#pragma unroll
    for (int e = 3; e <= 10; ++e) {   // edges entirely in tid bits: thread-constant
        int hi = 11 - e, lo = 10 - e;
        phi0 += (((tid >> hi) ^ (tid >> lo)) & 1) ? zh[e] : -zh[e];
    }
    float z0 = zh[0], z1 = zh[1], z2 = zh[2], z11 = zh[11];
    int t8 = (tid >> 8) & 1, t0 = tid & 1;
#pragma unroll
    for (int j = 0; j < 8; ++j) {
        int j0 = j & 1, j1 = (j >> 1) & 1, j2 = (j >> 2) & 1;
        float phi = phi0
            + ((j2 ^ j1) ? z0 : -z0)       // (11,10)
            + ((j1 ^ j0) ? z1 : -z1)       // (10,9)
            + ((j0 ^ t8) ? z2 : -z2)       // (9,8)
            + ((j2 ^ t0) ? z11 : -z11);    // (11,0)
        float sp, cp;
        __sincosf(phi, &sp, &cp);
        amp[j] = cmulp(mkv(cp, sp), amp[j]);
    }
}

// ---- composed CNOT-ring source index ----
__device__ __forceinline__ int cnot_src(int k) {
#pragma unroll
    for (int e = 11; e >= 0; --e) {
        int hi = (e < 11) ? 11 - e : 11, lo = (e < 11) ? 10 - e : 0;
        if ((k >> hi) & 1) k ^= (1 << lo);
    }
    return k;
}

__device__ __forceinline__ void cnot_trip(v2f* amp, int tid, const int* kslot, v2f* b) {
#pragma unroll
    for (int j = 0; j < 8; ++j) b[j * 512 + (tid ^ j)] = amp[j];  // L0 write
    __syncthreads();
#pragma unroll
    for (int j = 0; j < 8; ++j) amp[j] = b[kslot[j]];             // lands in L0
}

__global__ __launch_bounds__(NT) void qsim_kernel(
    const float* __restrict__ data,       // [64,12]
    const float* __restrict__ enc_scale,  // [12,3]
    const float* __restrict__ enc_bias,   // [12,3]
    const float* __restrict__ eta,        // [1,3]
    const float* __restrict__ ew_zz,      // [1,12]
    const float* __restrict__ ew_xx,      // [1,12]
    const float* __restrict__ ew_yy,      // [1,12]
    const float* __restrict__ nb_z,       // [1,12]
    const float* __restrict__ nb_x,       // [1,12]
    const float* __restrict__ nb_y,       // [1,12]
    const float* __restrict__ trots,      // [1,3,12,3]
    float* __restrict__ out)              // [64,12]
{
    __shared__ v2f bbuf[2][QDIM];   // 64 KB barrier double buffer
    __shared__ v2f ibuf[QDIM];      // 32 KB intra-wave buffer (512 v2f per wave)
    __shared__ v2f g1q[72][4];      // fused 1q matrices
    __shared__ float zhalf[3][12];
    __shared__ float red[8][12];

    const int tid = threadIdx.x;
    const int l = tid & 63, wv = tid >> 6;
    const int bat = blockIdx.x;
    v2f* wb = &ibuf[wv * 512];      // wave-private region

    // ---- fused gate tables (Ising basis changes folded into neighbors) ----
    if (tid < 36) {                      // encoding: b = tid/12, q = tid%12
        int b = tid / 12, q = tid % 12;
        float x  = data[bat * 12 + q];
        float ax = enc_scale[q * 3 + 0] * x + enc_bias[q * 3 + 0];
        float ay = enc_scale[q * 3 + 1] * x + enc_bias[q * 3 + 1];
        float az = enc_scale[q * 3 + 2] * x + enc_bias[q * 3 + 2];
        M2 M;
        if (b == 0)      M = mmul(mrz(az), mmul(mry(ay), mrx(ax)));   // ZZ: no basis change
        else if (b == 1) M = mmul(mH(), mmul(mry(ay), mrx(ax)));      // XX: H after enc
        else             M = mmul(mW(), mmul(mrz(az), mry(ay)));      // YY: W after enc
        g1q[tid][0] = mkv(M.a.x, M.a.y); g1q[tid][1] = mkv(M.b.x, M.b.y);
        g1q[tid][2] = mkv(M.c.x, M.c.y); g1q[tid][3] = mkv(M.d.x, M.d.y);
    } else if (tid < 72) {               // bias + trainables (+ closing basis change first)
        int i = tid - 36, b = i / 12, q = i % 12;
        float nb = (b == 0) ? nb_z[q] : (b == 1) ? nb_x[q] : nb_y[q];
        M2 M0 = (b == 0) ? mrz(nb) : (b == 1) ? mrx(nb) : mry(nb);
        float t0 = trots[(b * 12 + q) * 3 + 0];
        float t1 = trots[(b * 12 + q) * 3 + 1];
        float t2 = trots[(b * 12 + q) * 3 + 2];
        M2 M = mmul(mrz(t2), mmul(mry(t1), mmul(mrx(t0), M0)));
        if (b == 1)      M = mmul(M, mH());    // closes the XX sandwich
        else if (b == 2) M = mmul(M, mWd());   // closes the YY sandwich
        g1q[tid][0] = mkv(M.a.x, M.a.y); g1q[tid][1] = mkv(M.b.x, M.b.y);
        g1q[tid][2] = mkv(M.c.x, M.c.y); g1q[tid][3] = mkv(M.d.x, M.d.y);
    } else if (tid < 108) {              // diagonal half-angles per block/edge
        int i = tid - 72, b = i / 12, e = i % 12;
        const float* ew = (b == 0) ? ew_zz : (b == 1) ? ew_xx : ew_yy;
        zhalf[b][e] = 0.5f * eta[b] * ew[e];
    }
    __syncthreads();

    // ---- state: L0, k = (tid<<3)|j ----
    v2f amp[8];
#pragma unroll
    for (int j = 0; j < 8; ++j) amp[j] = mkv(0.f, 0.f);
    if (tid == 0) amp[0].x = 1.f;

    // precompute CNOT-ring gather slots (same permutation every block)
    int kslot[8];
#pragma unroll
    for (int j = 0; j < 8; ++j)
        kslot[j] = slot0(cnot_src(kOf<0>(tid, j)));

    int sel = 0;
#define NB (&bbuf[(sel ^= 1) ^ 1][0])

    for (int blk = 0; blk < 3; ++blk) {
        const v2f(*Ge)[4] = &g1q[blk * 12];
        const v2f(*Gb)[4] = &g1q[36 + blk * 12];

        // ---- encoding (+opening basis change): L0 -> L1 -> L2 -> L3 ----
        g1_reg<0>(amp, Ge[0]);  g1_reg<1>(amp, Ge[1]);  g1_reg<2>(amp, Ge[2]);
        itrip<0>(amp, l, wb);                       // L0 -> L1 (no barrier)
        g1_reg<0>(amp, Ge[3]);  g1_reg<1>(amp, Ge[4]);  g1_reg<2>(amp, Ge[5]);
        itrip<1>(amp, l, wb);                       // L1 -> L2 (no barrier)
        g1_reg<0>(amp, Ge[6]);  g1_reg<1>(amp, Ge[7]);  g1_reg<2>(amp, Ge[8]);
        btrip(amp, tid, l, wv, NB);                 // L2 -> L3 (barrier)
        g1_reg<0>(amp, Ge[9]);  g1_reg<1>(amp, Ge[10]); g1_reg<2>(amp, Ge[11]);

        // ---- Ising block == fused diagonal in the rotated basis (L3) ----
        diag_L3(amp, zhalf[blk], tid);

        // ---- (closing basis change+) bias + trots: L3 -> L2 -> L1 -> L0 ----
        g1_reg<0>(amp, Gb[9]);  g1_reg<1>(amp, Gb[10]); g1_reg<2>(amp, Gb[11]);
        btrip(amp, tid, l, wv, NB);                 // L3 -> L2 (barrier)
        g1_reg<0>(amp, Gb[6]);  g1_reg<1>(amp, Gb[7]);  g1_reg<2>(amp, Gb[8]);
        itrip<1>(amp, l, wb);                       // L2 -> L1 (no barrier)
        g1_reg<0>(amp, Gb[3]);  g1_reg<1>(amp, Gb[4]);  g1_reg<2>(amp, Gb[5]);
        itrip<0>(amp, l, wb);                       // L1 -> L0 (no barrier)
        g1_reg<0>(amp, Gb[0]);  g1_reg<1>(amp, Gb[1]);  g1_reg<2>(amp, Gb[2]);

        // ---- CNOT entangling ring (fused permutation, stays L0; barrier) ----
        cnot_trip(amp, tid, kslot, NB);
    }

    // ---- Pauli-Z expectations (state in L0: k = (tid<<3)|j) ----
    float pr[8];
#pragma unroll
    for (int j = 0; j < 8; ++j) pr[j] = amp[j].x * amp[j].x + amp[j].y * amp[j].y;
    float psum = 0.f;
#pragma unroll
    for (int j = 0; j < 8; ++j) psum += pr[j];

    float acc[12];
#pragma unroll
    for (int i = 0; i < 9; ++i)
        acc[i] = ((tid >> (8 - i)) & 1) ? -psum : psum;
#pragma unroll
    for (int i = 9; i < 12; ++i) {
        float s = 0.f;
        int bit = 11 - i;  // j-bit index
#pragma unroll
        for (int j = 0; j < 8; ++j)
            s += ((j >> bit) & 1) ? -pr[j] : pr[j];
        acc[i] = s;
    }
#pragma unroll
    for (int off = 32; off > 0; off >>= 1)
#pragma unroll
        for (int i = 0; i < 12; ++i)
            acc[i] += __shfl_down(acc[i], off, 64);
    if ((tid & 63) == 0)
#pragma unroll
        for (int i = 0; i < 12; ++i) red[wv][i] = acc[i];
    __syncthreads();
    if (tid < 12) {
        float s = 0.f;
#pragma unroll
        for (int ww = 0; ww < 8; ++ww) s += red[ww][tid];
        out[bat * 12 + tid] = s;
    }
}

extern "C" void kernel_launch(void* const* d_in, const int* in_sizes, int n_in,
                              void* d_out, int out_size, void* d_ws, size_t ws_size,
                              hipStream_t stream) {
    const float* data      = (const float*)d_in[0];
    const float* enc_scale = (const float*)d_in[1];
    const float* enc_bias  = (const float*)d_in[2];
    const float* eta       = (const float*)d_in[3];
    const float* ew_zz     = (const float*)d_in[4];
    const float* ew_xx     = (const float*)d_in[5];
    const float* ew_yy     = (const float*)d_in[6];
    const float* nb_z      = (const float*)d_in[7];
    const float* nb_x      = (const float*)d_in[8];
    const float* nb_y      = (const float*)d_in[9];
    const float* trots     = (const float*)d_in[10];
    float* out = (float*)d_out;

    int batch = out_size / 12;  // 64
    qsim_kernel<<<batch, NT, 0, stream>>>(data, enc_scale, enc_bias, eta,
                                          ew_zz, ew_xx, ew_yy,
                                          nb_z, nb_x, nb_y, trots, out);
}

// Round 9
// 94.517 us; speedup vs baseline: 1.0718x; 1.0054x over previous
//
#include <hip/hip_runtime.h>
#include <math.h>

#define NT 512
#define QDIM 4096   // 2^12

typedef float v2f __attribute__((ext_vector_type(2)));
using F2 = float2;

__device__ __forceinline__ v2f mkv(float x, float y) { v2f r; r.x = x; r.y = y; return r; }

// ---- packed complex ops (VOP3P dual-FP32) ----
__device__ __forceinline__ v2f cfma(v2f m, v2f a, v2f acc) {   // acc + m*a (complex)
    v2f r;
    asm("v_pk_fma_f32 %0, %1, %2, %3 op_sel:[0,0,0] op_sel_hi:[0,1,1]\n\t"
        "v_pk_fma_f32 %0, %1, %2, %0 op_sel:[1,1,0] op_sel_hi:[1,0,1] neg_lo:[1,0,0]"
        : "=&v"(r) : "v"(m), "v"(a), "v"(acc));
    return r;
}
__device__ __forceinline__ v2f cmulp(v2f m, v2f a) {           // m*a (complex)
    v2f r;
    asm("v_pk_mul_f32 %0, %1, %2 op_sel:[0,0] op_sel_hi:[0,1]\n\t"
        "v_pk_fma_f32 %0, %1, %2, %0 op_sel:[1,1,0] op_sel_hi:[1,0,1] neg_lo:[1,0,0]"
        : "=&v"(r) : "v"(m), "v"(a));
    return r;
}

// ---- scalar complex helpers for the table build (once per block) ----
__device__ __forceinline__ F2 cadd(F2 p, F2 q) { return make_float2(p.x + q.x, p.y + q.y); }
__device__ __forceinline__ F2 cmul(F2 p, F2 q) {
    return make_float2(p.x * q.x - p.y * q.y, p.x * q.y + p.y * q.x);
}
struct M2 { F2 a, b, c, d; };
__device__ __forceinline__ M2 mmul(M2 A, M2 B) {
    M2 R;
    R.a = cadd(cmul(A.a, B.a), cmul(A.b, B.c));
    R.b = cadd(cmul(A.a, B.b), cmul(A.b, B.d));
    R.c = cadd(cmul(A.c, B.a), cmul(A.d, B.c));
    R.d = cadd(cmul(A.c, B.b), cmul(A.d, B.d));
    return R;
}
__device__ __forceinline__ M2 mrx(float t) {
    float s, c; sincosf(0.5f * t, &s, &c);
    return { make_float2(c, 0), make_float2(0, -s), make_float2(0, -s), make_float2(c, 0) };
}
__device__ __forceinline__ M2 mry(float t) {
    float s, c; sincosf(0.5f * t, &s, &c);
    return { make_float2(c, 0), make_float2(-s, 0), make_float2(s, 0), make_float2(c, 0) };
}
__device__ __forceinline__ M2 mrz(float t) {
    float s, c; sincosf(0.5f * t, &s, &c);
    return { make_float2(c, -s), make_float2(0, 0), make_float2(0, 0), make_float2(c, s) };
}
#define RSQ2 0.70710678118654752f
__device__ __forceinline__ M2 mH() {
    return { make_float2(RSQ2, 0), make_float2(RSQ2, 0), make_float2(RSQ2, 0), make_float2(-RSQ2, 0) };
}
__device__ __forceinline__ M2 mW() {   // W = H*S; W† Z W = -Y => YY = W†⊗W† ZZ W⊗W
    return { make_float2(RSQ2, 0), make_float2(0, RSQ2), make_float2(RSQ2, 0), make_float2(0, -RSQ2) };
}
__device__ __forceinline__ M2 mWd() {
    return { make_float2(RSQ2, 0), make_float2(RSQ2, 0), make_float2(0, -RSQ2), make_float2(0, RSQ2) };
}

// ================= layouts =================
// tid = wv*64 + l.  Layout Li: register-local j = qubits {3Li..3Li+2}
// L0: k = j | l<<3 | wv<<9          L1: k = (l&7) | j<<3 | (l>>3)<<6 | wv<<9
// L2: k = l | j<<6 | wv<<9          L3: k = l | wv<<6 | j<<9

template<int Li>
__device__ __forceinline__ int kOf(int t, int j) {
    const int mlo = (1 << (3 * Li)) - 1;
    return (t & mlo) | (j << (3 * Li)) | ((t & ~mlo) << 3);
}
__device__ __forceinline__ int slot0(int k) {
    int j = k & 7, t = k >> 3;
    return j * 512 + (t ^ j);
}

// ---- intra-wave trips (wave-private 512-v2f region wb, NO barrier) ----
template<int TYPE>   // TYPE 0: <0,1>/<1,0>   TYPE 1: <1,2>/<2,1>
__device__ __forceinline__ void itrip(v2f* amp, int l, v2f* wb) {
#pragma unroll
    for (int j = 0; j < 8; ++j) wb[j * 64 + (l ^ ((9 * j) & 63))] = amp[j];
    asm volatile("" ::: "memory");   // compiler fence; DS pipe is in-order per wave
#pragma unroll
    for (int j = 0; j < 8; ++j) {
        int jo, lo;
        if (TYPE == 0) { jo = l & 7;        lo = j | (l & 56); }
        else           { jo = (l >> 3) & 7; lo = (l & 7) | (j << 3); }
        amp[j] = wb[jo * 64 + (lo ^ ((9 * jo) & 63))];
    }
}

// ---- barrier trip <2,3> / <3,2> (involution: same formula both ways) ----
__device__ __forceinline__ void btrip(v2f* amp, int tid, int l, int wv, v2f* b) {
#pragma unroll
    for (int j = 0; j < 8; ++j) b[j * 512 + (tid ^ j)] = amp[j];
    __syncthreads();
#pragma unroll
    for (int j = 0; j < 8; ++j) amp[j] = b[wv * 512 + ((j * 64 + l) ^ wv)];
}

// ---- gate-matrix trio: 12 v2f in registers, loaded via 6x ds_read_b128 ----
struct Trio { v2f m[12]; };

__device__ __forceinline__ Trio load_trio(const float4 (*g4)[2]) {
    Trio t;
#pragma unroll
    for (int k = 0; k < 3; ++k) {
        float4 a = g4[k][0], b = g4[k][1];
        t.m[k * 4 + 0] = mkv(a.x, a.y); t.m[k * 4 + 1] = mkv(a.z, a.w);
        t.m[k * 4 + 2] = mkv(b.x, b.y); t.m[k * 4 + 3] = mkv(b.z, b.w);
    }
    return t;
}

// ---- 1q register gate on local j-bit JB (matrix already in registers) ----
template<int JB>
__device__ __forceinline__ void g1_reg(v2f* amp, const v2f* g) {
    const int m = 1 << JB;
    v2f m00 = g[0], m01 = g[1], m10 = g[2], m11 = g[3];
#pragma unroll
    for (int j = 0; j < 8; ++j)
        if (!(j & m)) {
            v2f a = amp[j], b = amp[j | m];
            amp[j]     = cfma(m01, b, cmulp(m00, a));
            amp[j | m] = cfma(m11, b, cmulp(m10, a));
        }
}
__device__ __forceinline__ void apply_trio(v2f* amp, const Trio& t) {
    g1_reg<0>(amp, t.m + 0);  g1_reg<1>(amp, t.m + 4);  g1_reg<2>(amp, t.m + 8);
}

// ---- fused diagonal Ising phase (all 12 ring edges) in L3: k = tid(0-8) | j<<9 ----
__device__ __forceinline__ void diag_L3(v2f* amp, const float* zh, int tid) {
    float phi0 = 0.f;
#pragma unroll
    for (int e = 3; e <= 10; ++e) {   // edges entirely in tid bits: thread-constant
        int hi = 11 - e, lo = 10 - e;
        phi0 += (((tid >> hi) ^ (tid >> lo)) & 1) ? zh[e] : -zh[e];
    }
    float z0 = zh[0], z1 = zh[1], z2 = zh[2], z11 = zh[11];
    int t8 = (tid >> 8) & 1, t0 = tid & 1;
#pragma unroll
    for (int j = 0; j < 8; ++j) {
        int j0 = j & 1, j1 = (j >> 1) & 1, j2 = (j >> 2) & 1;
        float phi = phi0
            + ((j2 ^ j1) ? z0 : -z0)       // (11,10)
            + ((j1 ^ j0) ? z1 : -z1)       // (10,9)
            + ((j0 ^ t8) ? z2 : -z2)       // (9,8)
            + ((j2 ^ t0) ? z11 : -z11);    // (11,0)
        float sp, cp;
        __sincosf(phi, &sp, &cp);
        amp[j] = cmulp(mkv(cp, sp), amp[j]);
    }
}

// ---- composed CNOT-ring source index ----
__device__ __forceinline__ int cnot_src(int k) {
#pragma unroll
    for (int e = 11; e >= 0; --e) {
        int hi = (e < 11) ? 11 - e : 11, lo = (e < 11) ? 10 - e : 0;
        if ((k >> hi) & 1) k ^= (1 << lo);
    }
    return k;
}

__device__ __forceinline__ void cnot_trip(v2f* amp, int tid, const int* kslot, v2f* b) {
#pragma unroll
    for (int j = 0; j < 8; ++j) b[j * 512 + (tid ^ j)] = amp[j];  // L0 write
    __syncthreads();
#pragma unroll
    for (int j = 0; j < 8; ++j) amp[j] = b[kslot[j]];             // lands in L0
}

__global__ __launch_bounds__(NT) void qsim_kernel(
    const float* __restrict__ data,       // [64,12]
    const float* __restrict__ enc_scale,  // [12,3]
    const float* __restrict__ enc_bias,   // [12,3]
    const float* __restrict__ eta,        // [1,3]
    const float* __restrict__ ew_zz,      // [1,12]
    const float* __restrict__ ew_xx,      // [1,12]
    const float* __restrict__ ew_yy,      // [1,12]
    const float* __restrict__ nb_z,       // [1,12]
    const float* __restrict__ nb_x,       // [1,12]
    const float* __restrict__ nb_y,       // [1,12]
    const float* __restrict__ trots,      // [1,3,12,3]
    float* __restrict__ out)              // [64,12]
{
    __shared__ v2f bbuf[2][QDIM];     // 64 KB barrier double buffer
    __shared__ v2f ibuf[QDIM];        // 32 KB intra-wave buffer (512 v2f per wave)
    __shared__ float4 g1q4[72][2];    // fused 1q matrices, 32 B each -> 2x b128 loads
    __shared__ float zhalf[3][12];
    __shared__ float red[8][12];

    const int tid = threadIdx.x;
    const int l = tid & 63, wv = tid >> 6;
    const int bat = blockIdx.x;
    v2f* wb = &ibuf[wv * 512];        // wave-private region

    // ---- fused gate tables (Ising basis changes folded into neighbors) ----
    if (tid < 36) {                      // encoding: b = tid/12, q = tid%12
        int b = tid / 12, q = tid % 12;
        float x  = data[bat * 12 + q];
        float ax = enc_scale[q * 3 + 0] * x + enc_bias[q * 3 + 0];
        float ay = enc_scale[q * 3 + 1] * x + enc_bias[q * 3 + 1];
        float az = enc_scale[q * 3 + 2] * x + enc_bias[q * 3 + 2];
        M2 M;
        if (b == 0)      M = mmul(mrz(az), mmul(mry(ay), mrx(ax)));   // ZZ: no basis change
        else if (b == 1) M = mmul(mH(), mmul(mry(ay), mrx(ax)));      // XX: H after enc
        else             M = mmul(mW(), mmul(mrz(az), mry(ay)));      // YY: W after enc
        g1q4[tid][0] = make_float4(M.a.x, M.a.y, M.b.x, M.b.y);
        g1q4[tid][1] = make_float4(M.c.x, M.c.y, M.d.x, M.d.y);
    } else if (tid < 72) {               // bias + trainables (+ closing basis change first)
        int i = tid - 36, b = i / 12, q = i % 12;
        float nb = (b == 0) ? nb_z[q] : (b == 1) ? nb_x[q] : nb_y[q];
        M2 M0 = (b == 0) ? mrz(nb) : (b == 1) ? mrx(nb) : mry(nb);
        float t0 = trots[(b * 12 + q) * 3 + 0];
        float t1 = trots[(b * 12 + q) * 3 + 1];
        float t2 = trots[(b * 12 + q) * 3 + 2];
        M2 M = mmul(mrz(t2), mmul(mry(t1), mmul(mrx(t0), M0)));
        if (b == 1)      M = mmul(M, mH());    // closes the XX sandwich
        else if (b == 2) M = mmul(M, mWd());   // closes the YY sandwich
        g1q4[tid][0] = make_float4(M.a.x, M.a.y, M.b.x, M.b.y);
        g1q4[tid][1] = make_float4(M.c.x, M.c.y, M.d.x, M.d.y);
    } else if (tid < 108) {              // diagonal half-angles per block/edge
        int i = tid - 72, b = i / 12, e = i % 12;
        const float* ew = (b == 0) ? ew_zz : (b == 1) ? ew_xx : ew_yy;
        zhalf[b][e] = 0.5f * eta[b] * ew[e];
    }
    __syncthreads();

    // ---- state: L0, k = (tid<<3)|j ----
    v2f amp[8];
#pragma unroll
    for (int j = 0; j < 8; ++j) amp[j] = mkv(0.f, 0.f);
    if (tid == 0) amp[0].x = 1.f;

    // precompute CNOT-ring gather slots (same permutation every block)
    int kslot[8];
#pragma unroll
    for (int j = 0; j < 8; ++j)
        kslot[j] = slot0(cnot_src(kOf<0>(tid, j)));

    int sel = 0;
#define NB (&bbuf[(sel ^= 1) ^ 1][0])

    for (int blk = 0; blk < 3; ++blk) {
        const float4(*Ge)[2] = &g1q4[blk * 12];
        const float4(*Gb)[2] = &g1q4[36 + blk * 12];

        // ---- encoding (+opening basis change): L0 -> L1 -> L2 -> L3 ----
        // software-pipelined: load stage s+1's trio before applying stage s
        Trio tA = load_trio(Ge + 0);
        Trio tB = load_trio(Ge + 3);
        apply_trio(amp, tA);
        itrip<0>(amp, l, wb);                       // L0 -> L1 (no barrier)
        tA = load_trio(Ge + 6);
        apply_trio(amp, tB);
        itrip<1>(amp, l, wb);                       // L1 -> L2 (no barrier)
        tB = load_trio(Ge + 9);
        apply_trio(amp, tA);
        btrip(amp, tid, l, wv, NB);                 // L2 -> L3 (barrier)
        tA = load_trio(Gb + 9);
        apply_trio(amp, tB);

        // ---- Ising block == fused diagonal in the rotated basis (L3) ----
        diag_L3(amp, zhalf[blk], tid);

        // ---- (closing basis change+) bias + trots: L3 -> L2 -> L1 -> L0 ----
        apply_trio(amp, tA);
        btrip(amp, tid, l, wv, NB);                 // L3 -> L2 (barrier)
        tA = load_trio(Gb + 6);
        tB = load_trio(Gb + 3);
        apply_trio(amp, tA);
        itrip<1>(amp, l, wb);                       // L2 -> L1 (no barrier)
        tA = load_trio(Gb + 0);
        apply_trio(amp, tB);
        itrip<0>(amp, l, wb);                       // L1 -> L0 (no barrier)
        apply_trio(amp, tA);

        // ---- CNOT entangling ring (fused permutation, stays L0; barrier) ----
        cnot_trip(amp, tid, kslot, NB);
    }

    // ---- Pauli-Z expectations (state in L0: k = (tid<<3)|j) ----
    float pr[8];
#pragma unroll
    for (int j = 0; j < 8; ++j) pr[j] = amp[j].x * amp[j].x + amp[j].y * amp[j].y;
    float psum = 0.f;
#pragma unroll
    for (int j = 0; j < 8; ++j) psum += pr[j];

    float acc[12];
#pragma unroll
    for (int i = 0; i < 9; ++i)
        acc[i] = ((tid >> (8 - i)) & 1) ? -psum : psum;
#pragma unroll
    for (int i = 9; i < 12; ++i) {
        float s = 0.f;
        int bit = 11 - i;  // j-bit index
#pragma unroll
        for (int j = 0; j < 8; ++j)
            s += ((j >> bit) & 1) ? -pr[j] : pr[j];
        acc[i] = s;
    }
#pragma unroll
    for (int off = 32; off > 0; off >>= 1)
#pragma unroll
        for (int i = 0; i < 12; ++i)
            acc[i] += __shfl_down(acc[i], off, 64);
    if ((tid & 63) == 0)
#pragma unroll
        for (int i = 0; i < 12; ++i) red[wv][i] = acc[i];
    __syncthreads();
    if (tid < 12) {
        float s = 0.f;
#pragma unroll
        for (int ww = 0; ww < 8; ++ww) s += red[ww][tid];
        out[bat * 12 + tid] = s;
    }
}

extern "C" void kernel_launch(void* const* d_in, const int* in_sizes, int n_in,
                              void* d_out, int out_size, void* d_ws, size_t ws_size,
                              hipStream_t stream) {
    const float* data      = (const float*)d_in[0];
    const float* enc_scale = (const float*)d_in[1];
    const float* enc_bias  = (const float*)d_in[2];
    const float* eta       = (const float*)d_in[3];
    const float* ew_zz     = (const float*)d_in[4];
    const float* ew_xx     = (const float*)d_in[5];
    const float* ew_yy     = (const float*)d_in[6];
    const float* nb_z      = (const float*)d_in[7];
    const float* nb_x      = (const float*)d_in[8];
    const float* nb_y      = (const float*)d_in[9];
    const float* trots     = (const float*)d_in[10];
    float* out = (float*)d_out;

    int batch = out_size / 12;  // 64
    qsim_kernel<<<batch, NT, 0, stream>>>(data, enc_scale, enc_bias, eta,
                                          ew_zz, ew_xx, ew_yy,
                                          nb_z, nb_x, nb_y, trots, out);
}